// Round 6
// baseline (730.391 us; speedup 1.0000x reference)
//
#include <hip/hip_runtime.h>
#include <hip/hip_fp16.h>

typedef __attribute__((ext_vector_type(8)))  _Float16 half8;
typedef __attribute__((ext_vector_type(16))) float    f32x16;

#define B_   16
#define NPTS 4096                      // points per batch (N == M == 4096)

constexpr int BLK  = 512;              // 8 waves per block
constexpr int WV   = 8;
constexpr int QF   = 2;                // query fragments per wave (64 queries)
constexpr int TF   = 2;                // target tiles per loop step
constexpr int QPW  = 32 * QF;          // 64 queries per wave
constexpr int TSPL = 2;                // target splits (waves sharing a query group)
constexpr int QG   = WV / TSPL;        // 4 query groups per block
constexpr int QPB  = QG * QPW;         // 256 queries per block
constexpr int NQC  = NPTS / QPB;       // 16 query chunks
constexpr int TPS  = NPTS / TSPL;      // 2048 targets per split
constexpr int TPW  = TPS / 32;         // 64 tiles of 32 targets per wave
constexpr int NIT  = TPW / TF;         // 32 loop steps (2 tiles each)
constexpr int NBLK = 2 * B_ * NQC;     // 512 blocks (2 per CU)

__device__ __forceinline__ float min3f(float a, float b, float c) {
    return fminf(fminf(a, b), c);      // -> v_min3_f32
}

__device__ __forceinline__ float tree16(const f32x16& d) {
    float a0 = min3f(d[0],  d[1],  d[2]);
    float a1 = min3f(d[3],  d[4],  d[5]);
    float a2 = min3f(d[6],  d[7],  d[8]);
    float a3 = min3f(d[9],  d[10], d[11]);
    float a4 = min3f(d[12], d[13], d[14]);
    return fminf(min3f(a0, a1, a2), min3f(a3, a4, d[15]));
}

// ------------------------------------------------------------------
// R6 = R4 structure (QF=2 x TF=2, ~110 VGPR -- the proven envelope;
// R5's QF=4 blew the 128-reg cap and regressed 30%) + two phase-local
// cuts:
//  (1) masked K-dedup: A-frag lanes>=32 held a DUPLICATE of the K-low
//      half (K-dup trick, hence the old 0.5x). Now hi-lanes supply a
//      zero fragment instead of re-reading the same 16 B -> exec-masked
//      ds_read_b128 moves 512 B/wave instead of 1024 -> LDS return-path
//      traffic halves. D = S (not 2S); epilogue: dd = v + q2.
//  (2) vectorized staging: 3x float4 per 4 points (24 scalar dword
//      loads/thread -> 6 x dwordx4).
// Math otherwise identical: A-row [-2x,-2y,-2z,g2hi,g2lo,0,0,0],
// B-frag [x,y,z,1,1,0,0,0]; d^2 = minD + |q|^2.
__global__ __launch_bounds__(BLK, 4) void chamfer_mfma(
        const float* __restrict__ pred, const float* __restrict__ gt,
        float* __restrict__ accum, unsigned* __restrict__ counter,
        float* __restrict__ out) {
    const int qc  = blockIdx.x;
    const int b   = blockIdx.y;
    const int dir = blockIdx.z;
    const float* qsrc = dir ? gt   : pred;   // queries
    const float* tsrc = dir ? pred : gt;     // targets

    __shared__ uint4 sh[NPTS];               // 64 KB: all targets as A-frag rows
    __shared__ float sred[WV][QPW];          // 2 KB: per-wave per-query min d^2
    __shared__ float ps[QG];

    const int tid  = threadIdx.x;
    const int lane = tid & 63;
    const int wv   = tid >> 6;
    const int m    = lane & 31;
    const int qg   = wv >> 1;                // query group 0..3
    const int ts   = wv & 1;                 // target split 0..1

    // ---- B fragments: this lane's two queries (cols m and m+32) ----
    const float* qbase = qsrc + (b * NPTS + qc * QPB + qg * QPW) * 3;
    half8 bfrag[QF];
    float q2[QF];
#pragma unroll
    for (int f = 0; f < QF; ++f) {
        const float* qp = qbase + (f * 32 + m) * 3;
        __half hqx = __float2half(qp[0]);
        __half hqy = __float2half(qp[1]);
        __half hqz = __float2half(qp[2]);
        float fqx = __half2float(hqx), fqy = __half2float(hqy), fqz = __half2float(hqz);
        q2[f] = fmaf(fqx, fqx, fmaf(fqy, fqy, fqz * fqz));
        uint4 bu;
        bu.x = (unsigned)__half_as_ushort(hqx) | ((unsigned)__half_as_ushort(hqy) << 16);
        bu.y = (unsigned)__half_as_ushort(hqz) | (0x3C00u << 16);   // {z, 1.0}
        bu.z = 0x3C00u;                                             // {1.0, 0}
        bu.w = 0u;
        bfrag[f] = __builtin_bit_cast(half8, bu);
    }

    f32x16 zero;
#pragma unroll
    for (int i = 0; i < 16; ++i) zero[i] = 0.0f;

    // ---- stage ALL 4096 targets as A-frag rows (float4-vectorized) ----
    const float4* tp4 = reinterpret_cast<const float4*>(tsrc + b * NPTS * 3);
#pragma unroll
    for (int k = 0; k < NPTS / (4 * BLK); ++k) {    // 2 super-iters x 4 points
        const int tq = k * BLK + tid;               // quad index
        const float4 f0 = tp4[tq * 3 + 0];
        const float4 f1 = tp4[tq * 3 + 1];
        const float4 f2 = tp4[tq * 3 + 2];
        const float px[4] = {f0.x, f0.w, f1.z, f2.y};
        const float py[4] = {f0.y, f1.x, f1.w, f2.z};
        const float pz[4] = {f0.z, f1.y, f2.x, f2.w};
#pragma unroll
        for (int i = 0; i < 4; ++i) {
            __half hx = __float2half(px[i]);
            __half hy = __float2half(py[i]);
            __half hz = __float2half(pz[i]);
            float fx = __half2float(hx), fy = __half2float(hy), fz = __half2float(hz);
            float g2 = fmaf(fx, fx, fmaf(fy, fy, fz * fz));
            __half ax = __float2half(-2.0f * fx);
            __half ay = __float2half(-2.0f * fy);
            __half az = __float2half(-2.0f * fz);
            __half g2hi = __float2half(g2);
            __half g2lo = __float2half(g2 - __half2float(g2hi));
            uint4 w;
            w.x = (unsigned)__half_as_ushort(ax) | ((unsigned)__half_as_ushort(ay) << 16);
            w.y = (unsigned)__half_as_ushort(az) | ((unsigned)__half_as_ushort(g2hi) << 16);
            w.z = (unsigned)__half_as_ushort(g2lo);
            w.w = 0u;
            sh[tq * 4 + i] = w;
        }
    }
    __syncthreads();

    // ---- sweep this wave's 64 tiles, 2 tiles x 2 qfrags per step.
    //      Masked dedup: only lanes 0-31 read LDS (A K-low half); lanes
    //      32-63 feed zeros (K-high half) -> D = S directly. ----
    const uint4* shp = sh + ts * TPS + m;    // lane base (lanes 0-31 only)
    float mn0 = 1e30f, mn1 = 1e30f;
#pragma unroll 8
    for (int t = 0; t < NIT; ++t) {
        uint4 au0 = {0u, 0u, 0u, 0u};
        uint4 au1 = {0u, 0u, 0u, 0u};
        if (lane < 32) {
            au0 = shp[t * 64];               // tile 2t   (byte off t*1024)
            au1 = shp[t * 64 + 32];          // tile 2t+1 (byte off t*1024+512)
        }
        half8 a0 = __builtin_bit_cast(half8, au0);
        half8 a1 = __builtin_bit_cast(half8, au1);
        f32x16 d00 = __builtin_amdgcn_mfma_f32_32x32x16_f16(a0, bfrag[0], zero, 0, 0, 0);
        f32x16 d01 = __builtin_amdgcn_mfma_f32_32x32x16_f16(a0, bfrag[1], zero, 0, 0, 0);
        f32x16 d10 = __builtin_amdgcn_mfma_f32_32x32x16_f16(a1, bfrag[0], zero, 0, 0, 0);
        f32x16 d11 = __builtin_amdgcn_mfma_f32_32x32x16_f16(a1, bfrag[1], zero, 0, 0, 0);
        float t00 = tree16(d00);
        float t01 = tree16(d01);
        float t10 = tree16(d10);
        float t11 = tree16(d11);
        mn0 = min3f(mn0, t00, t10);
        mn1 = min3f(mn1, t01, t11);
    }

    // rows split across lane halves: full 32-row min needs lane ^ 32
    float v0 = fminf(mn0, __shfl_xor(mn0, 32));
    float v1 = fminf(mn1, __shfl_xor(mn1, 32));
    float dd0 = fmaxf(v0 + q2[0], 0.0f);             // fold |q|^2 (D = S now)
    float dd1 = fmaxf(v1 + q2[1], 0.0f);
    if (lane < 32) {                                 // lanes 32-63 hold duplicates
        sred[wv][m]      = dd0;
        sred[wv][m + 32] = dd1;
    }
    __syncthreads();

    // ---- combine 2 target splits per query, sqrt, block-sum ----
    float s = 0.0f;
    if (wv < QG) {                               // threads 0..255 = 256 queries
        const int g  = wv;                       // query group 0..3
        const int mm = lane;                     // query within group 0..63
        float d = fminf(sred[g * 2 + 0][mm], sred[g * 2 + 1][mm]);
        s = sqrtf(d);
        // butterfly sum over this wave's 64 lanes
#pragma unroll
        for (int off = 32; off; off >>= 1) s += __shfl_xor(s, off);
        if (lane == 0) ps[g] = s;
    }
    __syncthreads();

    if (tid == 0) {
        float bs = ps[0] + ps[1] + ps[2] + ps[3];
        atomicAdd(accum, bs);
        __threadfence();
        if (atomicAdd(counter, 1u) == NBLK - 1) {   // last block finalizes
            float total = atomicAdd(accum, 0.0f);   // coherent read
            float loss  = total * (1.0f / (float)(B_ * NPTS));
            out[0] = loss;          // WEIGHT * loss, WEIGHT = 1
            out[1] = loss;          // helper_loss
            out[2] = 0.1f * loss;   // helper_cderr = p1 chamfer * xyz_unit
        }
    }
}

// ------------------------------------------------------------------
extern "C" void kernel_launch(void* const* d_in, const int* in_sizes, int n_in,
                              void* d_out, int out_size, void* d_ws, size_t ws_size,
                              hipStream_t stream) {
    const float* pred = (const float*)d_in[0];
    const float* gt   = (const float*)d_in[1];
    float*    out     = (float*)d_out;
    float*    accum   = (float*)d_ws;
    unsigned* counter = (unsigned*)d_ws + 1;

    hipMemsetAsync(d_ws, 0, 8, stream);
    chamfer_mfma<<<dim3(NQC, B_, 2), BLK, 0, stream>>>(pred, gt, accum, counter, out);
}

// Round 7
// 78.820 us; speedup vs baseline: 9.2666x; 9.2666x over previous
//
#include <hip/hip_runtime.h>
#include <hip/hip_fp16.h>

typedef __attribute__((ext_vector_type(8)))  _Float16 half8;
typedef __attribute__((ext_vector_type(16))) float    f32x16;

#define B_   16
#define NPTS 4096                      // points per batch (N == M == 4096)

constexpr int BLK  = 512;              // 8 waves per block
constexpr int WV   = 8;
constexpr int QF   = 2;                // query fragments per wave (64 queries)
constexpr int TF   = 2;                // target tiles per loop step
constexpr int QPW  = 32 * QF;          // 64 queries per wave
constexpr int TSPL = 2;                // target splits (waves sharing a query group)
constexpr int QG   = WV / TSPL;        // 4 query groups per block
constexpr int QPB  = QG * QPW;         // 256 queries per block
constexpr int NQC  = NPTS / QPB;       // 16 query chunks
constexpr int TPS  = NPTS / TSPL;      // 2048 targets per split
constexpr int TPW  = TPS / 32;         // 64 tiles of 32 targets per wave
constexpr int NIT  = TPW / TF;         // 32 loop steps (2 tiles each)
constexpr int NBLK = 2 * B_ * NQC;     // 512 blocks (2 per CU)

__device__ __forceinline__ float min3f(float a, float b, float c) {
    return fminf(fminf(a, b), c);      // -> v_min3_f32
}

__device__ __forceinline__ float tree16(const f32x16& d) {
    float a0 = min3f(d[0],  d[1],  d[2]);
    float a1 = min3f(d[3],  d[4],  d[5]);
    float a2 = min3f(d[6],  d[7],  d[8]);
    float a3 = min3f(d[9],  d[10], d[11]);
    float a4 = min3f(d[12], d[13], d[14]);
    return fminf(min3f(a0, a1, a2), min3f(a3, a4, d[15]));
}

// ------------------------------------------------------------------
// R7 = R4 (the proven envelope: QF=2 x TF=2, ~110 VGPR, full-wave
// unmasked ds_reads with the free L/L+32 K-dup broadcast, 0.5x epilogue)
// + three safe deltas:
//  (1) float4-vectorized staging (R6's good half: 48B/thread contiguous).
//  (2) explicit depth-1 LDS prefetch: tile-pair t+1 is loaded before
//      computing t, hiding ~120cyc ds_read latency under 4 MFMAs+trees
//      instead of heading the dependency chain (+8 VGPR, fits 128 cap).
//  (3) s_setprio(1) around the MFMA cluster (T5; waves are NOT
//      barrier-locked in this loop -> arbitration regime).
// R6 lesson baked in: NEVER lane-mask an MFMA operand load (spill
// disaster: VGPR 64, 1.6GB scratch writes, 690us).
// Math identical to proven kernel: A-row [-2x,-2y,-2z,g2hi,g2lo,0,0,0],
// B-frag [x,y,z,1,1,0,0,0] -> D = 2(|g|^2 - 2 q.g); d^2 = 0.5*minD+|q|^2.
__global__ __launch_bounds__(BLK, 4) void chamfer_mfma(
        const float* __restrict__ pred, const float* __restrict__ gt,
        float* __restrict__ accum, unsigned* __restrict__ counter,
        float* __restrict__ out) {
    const int qc  = blockIdx.x;
    const int b   = blockIdx.y;
    const int dir = blockIdx.z;
    const float* qsrc = dir ? gt   : pred;   // queries
    const float* tsrc = dir ? pred : gt;     // targets

    __shared__ uint4 sh[NPTS];               // 64 KB: all targets as A-frag rows
    __shared__ float sred[WV][QPW];          // 2 KB: per-wave per-query min d^2
    __shared__ float ps[QG];

    const int tid  = threadIdx.x;
    const int lane = tid & 63;
    const int wv   = tid >> 6;
    const int m    = lane & 31;
    const int qg   = wv >> 1;                // query group 0..3
    const int ts   = wv & 1;                 // target split 0..1

    // ---- B fragments: this lane's two queries (cols m and m+32) ----
    const float* qbase = qsrc + (b * NPTS + qc * QPB + qg * QPW) * 3;
    half8 bfrag[QF];
    float q2[QF];
#pragma unroll
    for (int f = 0; f < QF; ++f) {
        const float* qp = qbase + (f * 32 + m) * 3;
        __half hqx = __float2half(qp[0]);
        __half hqy = __float2half(qp[1]);
        __half hqz = __float2half(qp[2]);
        float fqx = __half2float(hqx), fqy = __half2float(hqy), fqz = __half2float(hqz);
        q2[f] = fmaf(fqx, fqx, fmaf(fqy, fqy, fqz * fqz));
        uint4 bu;
        bu.x = (unsigned)__half_as_ushort(hqx) | ((unsigned)__half_as_ushort(hqy) << 16);
        bu.y = (unsigned)__half_as_ushort(hqz) | (0x3C00u << 16);   // {z, 1.0}
        bu.z = 0x3C00u;                                             // {1.0, 0}
        bu.w = 0u;
        bfrag[f] = __builtin_bit_cast(half8, bu);
    }

    f32x16 zero;
#pragma unroll
    for (int i = 0; i < 16; ++i) zero[i] = 0.0f;

    // ---- stage ALL 4096 targets as A-frag rows (float4-vectorized) ----
    const float4* tp4 = reinterpret_cast<const float4*>(tsrc + b * NPTS * 3);
#pragma unroll
    for (int k = 0; k < NPTS / (4 * BLK); ++k) {    // 2 super-iters x 4 points
        const int tq = k * BLK + tid;               // quad index
        const float4 f0 = tp4[tq * 3 + 0];
        const float4 f1 = tp4[tq * 3 + 1];
        const float4 f2 = tp4[tq * 3 + 2];
        const float px[4] = {f0.x, f0.w, f1.z, f2.y};
        const float py[4] = {f0.y, f1.x, f1.w, f2.z};
        const float pz[4] = {f0.z, f1.y, f2.x, f2.w};
#pragma unroll
        for (int i = 0; i < 4; ++i) {
            __half hx = __float2half(px[i]);
            __half hy = __float2half(py[i]);
            __half hz = __float2half(pz[i]);
            float fx = __half2float(hx), fy = __half2float(hy), fz = __half2float(hz);
            float g2 = fmaf(fx, fx, fmaf(fy, fy, fz * fz));
            __half ax = __float2half(-2.0f * fx);
            __half ay = __float2half(-2.0f * fy);
            __half az = __float2half(-2.0f * fz);
            __half g2hi = __float2half(g2);
            __half g2lo = __float2half(g2 - __half2float(g2hi));
            uint4 w;
            w.x = (unsigned)__half_as_ushort(ax) | ((unsigned)__half_as_ushort(ay) << 16);
            w.y = (unsigned)__half_as_ushort(az) | ((unsigned)__half_as_ushort(g2hi) << 16);
            w.z = (unsigned)__half_as_ushort(g2lo);
            w.w = 0u;
            sh[tq * 4 + i] = w;
        }
    }
    __syncthreads();

    // ---- sweep this wave's 64 tiles, 2 tiles x 2 qfrags per step,
    //      depth-1 prefetch (load t+1 while computing t) ----
    const uint4* shp = sh + ts * TPS + m;    // lane base (lanes L, L+32 share addr)
    float mn0 = 1e30f, mn1 = 1e30f;
    uint4 au0 = shp[0];                      // tile 0
    uint4 au1 = shp[32];                     // tile 1
#pragma unroll 8
    for (int t = 0; t < NIT; ++t) {
        const int tn = (t + 1) & (NIT - 1);  // wraps to 0 on last iter (harmless)
        uint4 nx0 = shp[tn * 64];
        uint4 nx1 = shp[tn * 64 + 32];
        half8 a0 = __builtin_bit_cast(half8, au0);
        half8 a1 = __builtin_bit_cast(half8, au1);
        __builtin_amdgcn_s_setprio(1);
        f32x16 d00 = __builtin_amdgcn_mfma_f32_32x32x16_f16(a0, bfrag[0], zero, 0, 0, 0);
        f32x16 d01 = __builtin_amdgcn_mfma_f32_32x32x16_f16(a0, bfrag[1], zero, 0, 0, 0);
        f32x16 d10 = __builtin_amdgcn_mfma_f32_32x32x16_f16(a1, bfrag[0], zero, 0, 0, 0);
        f32x16 d11 = __builtin_amdgcn_mfma_f32_32x32x16_f16(a1, bfrag[1], zero, 0, 0, 0);
        __builtin_amdgcn_s_setprio(0);
        float t00 = tree16(d00);
        float t01 = tree16(d01);
        float t10 = tree16(d10);
        float t11 = tree16(d11);
        mn0 = min3f(mn0, t00, t10);
        mn1 = min3f(mn1, t01, t11);
        au0 = nx0;
        au1 = nx1;
    }

    // rows split across lane halves: full 32-row min needs lane ^ 32
    float v0 = fminf(mn0, __shfl_xor(mn0, 32));
    float v1 = fminf(mn1, __shfl_xor(mn1, 32));
    float dd0 = fmaxf(fmaf(0.5f, v0, q2[0]), 0.0f);  // undo K-dup, fold |q|^2
    float dd1 = fmaxf(fmaf(0.5f, v1, q2[1]), 0.0f);
    if (lane < 32) {                                 // lanes 32-63 hold duplicates
        sred[wv][m]      = dd0;
        sred[wv][m + 32] = dd1;
    }
    __syncthreads();

    // ---- combine 2 target splits per query, sqrt, block-sum ----
    float s = 0.0f;
    if (wv < QG) {                               // threads 0..255 = 256 queries
        const int g  = wv;                       // query group 0..3
        const int mm = lane;                     // query within group 0..63
        float d = fminf(sred[g * 2 + 0][mm], sred[g * 2 + 1][mm]);
        s = sqrtf(d);
        // butterfly sum over this wave's 64 lanes
#pragma unroll
        for (int off = 32; off; off >>= 1) s += __shfl_xor(s, off);
        if (lane == 0) ps[g] = s;
    }
    __syncthreads();

    if (tid == 0) {
        float bs = ps[0] + ps[1] + ps[2] + ps[3];
        atomicAdd(accum, bs);
        __threadfence();
        if (atomicAdd(counter, 1u) == NBLK - 1) {   // last block finalizes
            float total = atomicAdd(accum, 0.0f);   // coherent read
            float loss  = total * (1.0f / (float)(B_ * NPTS));
            out[0] = loss;          // WEIGHT * loss, WEIGHT = 1
            out[1] = loss;          // helper_loss
            out[2] = 0.1f * loss;   // helper_cderr = p1 chamfer * xyz_unit
        }
    }
}

// ------------------------------------------------------------------
extern "C" void kernel_launch(void* const* d_in, const int* in_sizes, int n_in,
                              void* d_out, int out_size, void* d_ws, size_t ws_size,
                              hipStream_t stream) {
    const float* pred = (const float*)d_in[0];
    const float* gt   = (const float*)d_in[1];
    float*    out     = (float*)d_out;
    float*    accum   = (float*)d_ws;
    unsigned* counter = (unsigned*)d_ws + 1;

    hipMemsetAsync(d_ws, 0, 8, stream);
    chamfer_mfma<<<dim3(NQC, B_, 2), BLK, 0, stream>>>(pred, gt, accum, counter, out);
}